// Round 11
// baseline (239.393 us; speedup 1.0000x reference)
//
#include <hip/hip_runtime.h>
#include <math.h>
#include <stdint.h>

#define M_TOTAL 16384
#define DDIM    4096
#define EXP     64

typedef __attribute__((ext_vector_type(8)))  short bf16x8;
typedef __attribute__((ext_vector_type(16))) float f32x16;

__device__ inline uint32_t fbits(float f){ union{float f;uint32_t u;}c; c.f=f; return c.u; }
__device__ inline float    bitsf(uint32_t u){ union{uint32_t u;float f;}c; c.u=u; return c.f; }
__device__ inline bf16x8   asfrag(uint4 t){ return __builtin_bit_cast(bf16x8, t); }

// ---------------------------------------------------------------------------
// W pre-pack: split w/nw into 3 bf16 planes (truncation split, exact to 2^-24)
// stored in MFMA-B-fragment-linear order:
//   word index = (((s*256 + kt)*2 + nt)*3 + pl)*256 + lane*4 + j
//   lane = (e&31) + 32*((k>>3)&1), word j holds k-elems 2j,2j+1
// ---------------------------------------------------------------------------
__global__ __launch_bounds__(256) void wpack_prep(
    const float* __restrict__ w, const float* __restrict__ nw,
    uint32_t* __restrict__ wpack)
{
    const int t = blockIdx.x * 256 + threadIdx.x;     // 786432 words total
    const int jw   = t & 3;
    const int lane = (t >> 2) & 63;
    const int rest = t >> 8;                          // ((s*256+kt)*2+nt)*3+pl
    const int pl   = rest % 3;
    const int r2   = rest / 3;
    const int nt   = r2 & 1;
    const int kt   = (r2 >> 1) & 255;
    const int s    = r2 >> 9;

    const int k0 = kt * 16 + (lane >> 5) * 8 + 2 * jw;
    const int e  = nt * 32 + (lane & 31);
    const float* __restrict__ src = s ? nw : w;
    float f0 = src[(size_t)k0 * EXP + e];
    float f1 = src[(size_t)(k0 + 1) * EXP + e];
    uint32_t u0 = fbits(f0), u1 = fbits(f1);
    for (int l = 0; l < pl; ++l) {                    // peel to level pl
        f0 -= bitsf(u0 & 0xFFFF0000u);
        f1 -= bitsf(u1 & 0xFFFF0000u);
        u0 = fbits(f0); u1 = fbits(f1);
    }
    wpack[t] = (u0 >> 16) | (u1 & 0xFFFF0000u);       // [lo=elem2j, hi=elem2j+1]
}

// ---------------------------------------------------------------------------
// MFMA GEMM, wave-private pipeline with 512B-per-row burst staging:
// part[kp][row][e] = sum over k-plane of (x@w + noise@nw)
// Wave = 32 rows x 64 experts. A chunk = 32 rows x 128 k (16 KB), staged as
// 16 global_load_lds instrs = 2 rows x 512 B CONTIGUOUS each (4 sequential
// 128B lines per row visit). Pacing: 2 stages + 6 W-loads per kstep, chunk =
// 8 ksteps, double-buffered. ONE s_waitcnt vmcnt(0) per chunk, placed BEFORE
// the chunk's first issues (only needed-now ops outstanding: order-robust,
// zero over-wait). No barriers anywhere. Slot-XOR kq^(r&7) on source + read.
// LDS 4 waves x 2 x 16 KB = 128 KB -> 1 block/CU; pipeline depth carries BW.
// ---------------------------------------------------------------------------
template<int KSPLIT>
__global__ __launch_bounds__(256, 1) void router_mfma8(
    const float* __restrict__ x, const float* __restrict__ noise,
    const uint32_t* __restrict__ wpack, float* __restrict__ part)
{
    constexpr int KRANGE = DDIM / KSPLIT;   // k per plane
    constexpr int VPS    = KRANGE / 16;     // ksteps per slice
    constexpr int NU     = 2 * VPS;         // ksteps total
    constexpr int CPS    = KRANGE / 128;    // 128k-chunks per slice
    constexpr int NC     = 2 * CPS;         // chunks total (= NU/8)

    __shared__ float Alf[4][2][4096];       // [wave][buf][32 rows x 128 k] = 128 KB

    const int tid  = threadIdx.x;
    const int w_   = tid >> 6;
    const int lane = tid & 63;
    const int l31  = lane & 31;
    const int kh   = lane >> 5;             // k-half of the fragment

    const int rowBase = blockIdx.x * 128 + w_ * 32;
    const int kp      = blockIdx.y;

    f32x16 acc[2], macc[2];
#pragma unroll
    for (int b = 0; b < 2; ++b)
#pragma unroll
        for (int i = 0; i < 16; ++i) { acc[b][i] = 0.f; macc[b][i] = 0.f; }

    // ---- stage one instr: 2 rows x 512 B contiguous; source kq XOR-permuted
    //      (involution) so dest stays linear and reads are conflict-light
    const int sh = lane >> 5;               // row-in-pair
    const int sq = lane & 31;               // dest 16B slot within row half
    auto stageA = [&](int c1, int bufn, int j) {
        const int cc = (c1 < NC) ? c1 : (NC - 1);          // tail clamp
        const int sl = cc / CPS, ck = cc % CPS;
        const float* __restrict__ base = sl ? noise : x;
        const int r  = 2 * j + sh;                         // row-in-wave 0..31
        const int kq = sq ^ (r & 7);                       // logical 16B k-quad
        const float* src = base + (size_t)(rowBase + r) * DDIM
                         + kp * KRANGE + ck * 128 + kq * 4;
        __builtin_amdgcn_global_load_lds(
            (const __attribute__((address_space(1))) uint32_t*)src,
            (__attribute__((address_space(3))) uint32_t*)(&Alf[w_][bufn][j * 256]),
            16, 0, 0);
    };
    auto wSrc = [&](int t) -> const uint32_t* {
        const int tc = (t < NU) ? t : (NU - 1);            // tail clamp
        const int sl = tc / VPS, v = tc % VPS;
        return wpack + (size_t)(sl * 256 + kp * VPS + v) * 1536 + lane * 4;
    };

    // ---- read-side offsets (floats), static per phase after unroll
    const int rr = l31;
    const int rb = (rr >> 1) * 256 + (rr & 1) * 128;
    int o0[8], o1[8];
#pragma unroll
    for (int p = 0; p < 8; ++p) {
        o0[p] = rb + ((4 * p + 2 * kh)     ^ (rr & 7)) * 4;
        o1[p] = rb + ((4 * p + 2 * kh + 1) ^ (rr & 7)) * 4;
    }

    uint4 wbuf[2][6];

    // ---- prologue: W(0) -> wbuf[0]; stage all 16 instrs of chunk 0
    {
        const uint32_t* wp = wSrc(0);
#pragma unroll
        for (int f = 0; f < 6; ++f) wbuf[0][f] = *(const uint4*)(wp + f * 256);
#pragma unroll
        for (int j = 0; j < 16; ++j) stageA(0, 0, j);
    }

    for (int c = 0; c < NC; ++c) {
        const int bufc = c & 1;
#pragma unroll
        for (int p = 0; p < 8; ++p) {
            const int t = c * 8 + p;

            // chunk-boundary sync BEFORE new issues: outstanding here is only
            // W(t) + current chunk's tail stages (both needed NOW) -> vmcnt(0)
            // is exact, order-robust, and never over-waits.
            if (p == 0) asm volatile("s_waitcnt vmcnt(0)" ::: "memory");

            // (a) W(t+1) -> wbuf[(p+1)&1]: 6 dwordx4 from L2-resident wpack
            const uint32_t* wp = wSrc(t + 1);
#pragma unroll
            for (int f = 0; f < 6; ++f) wbuf[(p + 1) & 1][f] = *(const uint4*)(wp + f * 256);
            // (b) 2 burst-stages of chunk c+1 into the other buffer
            stageA(c + 1, bufc ^ 1, 2 * p);
            stageA(c + 1, bufc ^ 1, 2 * p + 1);

            // (c) A fragment from wave-private LDS (XOR slot, ~4-way b128)
            const float4 a0 = *(const float4*)&Alf[w_][bufc][o0[p]];
            const float4 a1 = *(const float4*)&Alf[w_][bufc][o1[p]];

            // split to 3 bf16 fragments (truncation split, exact to 2^-24)
            uint32_t fa1[4], fa2[4], fa3[4];
            const float in[8] = { a0.x, a0.y, a0.z, a0.w, a1.x, a1.y, a1.z, a1.w };
#pragma unroll
            for (int j = 0; j < 4; ++j) {
                const float a = in[2 * j], b = in[2 * j + 1];
                const uint32_t ha = fbits(a) & 0xFFFF0000u, hb = fbits(b) & 0xFFFF0000u;
                fa1[j] = (ha >> 16) | hb;
                const float ra = a - bitsf(ha), rb2 = b - bitsf(hb);
                const uint32_t ha2 = fbits(ra) & 0xFFFF0000u, hb2 = fbits(rb2) & 0xFFFF0000u;
                fa2[j] = (ha2 >> 16) | hb2;
                const float sa = ra - bitsf(ha2), sb = rb2 - bitsf(hb2);
                fa3[j] = (fbits(sa) >> 16) | (fbits(sb) & 0xFFFF0000u);
            }
            const bf16x8 a1f = asfrag(*(const uint4*)fa1);
            const bf16x8 a2f = asfrag(*(const uint4*)fa2);
            const bf16x8 a3f = asfrag(*(const uint4*)fa3);

#pragma unroll
            for (int nt = 0; nt < 2; ++nt) {
                const bf16x8 b1 = asfrag(wbuf[p & 1][nt * 3 + 0]);
                const bf16x8 b2 = asfrag(wbuf[p & 1][nt * 3 + 1]);
                const bf16x8 b3 = asfrag(wbuf[p & 1][nt * 3 + 2]);
                f32x16 cc = acc[nt];         // ascending-magnitude product order
                cc = __builtin_amdgcn_mfma_f32_32x32x16_bf16(a1f, b3, cc, 0, 0, 0);
                cc = __builtin_amdgcn_mfma_f32_32x32x16_bf16(a3f, b1, cc, 0, 0, 0);
                cc = __builtin_amdgcn_mfma_f32_32x32x16_bf16(a2f, b2, cc, 0, 0, 0);
                cc = __builtin_amdgcn_mfma_f32_32x32x16_bf16(a1f, b2, cc, 0, 0, 0);
                cc = __builtin_amdgcn_mfma_f32_32x32x16_bf16(a2f, b1, cc, 0, 0, 0);
                cc = __builtin_amdgcn_mfma_f32_32x32x16_bf16(a1f, b1, cc, 0, 0, 0);
                acc[nt] = cc;
            }

            // drain 64-k window into fp32 masters (static: p==3 / p==7)
            if (p == 3 || p == 7) {
#pragma unroll
                for (int b = 0; b < 2; ++b)
#pragma unroll
                    for (int i = 0; i < 16; ++i) { macc[b][i] += acc[b][i]; acc[b][i] = 0.f; }
            }
        }
    }

    // drain tail-clamped in-flight loads before LDS lifetime ends
    asm volatile("s_waitcnt vmcnt(0)" ::: "memory");

    // write plane; C/D layout (HW-verified): col=lane&31, row=(r&3)+8*(r>>2)+4*(lane>>5)
    float* __restrict__ out = part + (size_t)blockIdx.y * M_TOTAL * EXP;
#pragma unroll
    for (int nt = 0; nt < 2; ++nt)
#pragma unroll
        for (int r4 = 0; r4 < 16; ++r4) {
            const int orow = rowBase + (r4 & 3) + 8 * (r4 >> 2) + 4 * kh;
            out[(size_t)orow * EXP + nt * 32 + l31] = macc[nt][r4];
        }
}

// one wave per row: logits = f64 sum of planes; top-2 (jax tie-break: lower index
// wins); gates = 2-logit softmax == renormalized full softmax.
__global__ __launch_bounds__(256) void topk_epilogue3(
    const float* __restrict__ part, const int nplanes, float* __restrict__ outv)
{
    const int tid  = threadIdx.x;
    const int lane = tid & 63;
    const int row  = blockIdx.x * 4 + (tid >> 6);

    double sd = 0.0;
    for (int p = 0; p < nplanes; ++p)
        sd += (double)part[((size_t)p * M_TOTAL + row) * EXP + lane];
    const float logit = (float)sd;

    float v = logit; int idx = lane;
#pragma unroll
    for (int off = 32; off >= 1; off >>= 1) {
        const float vo = __shfl_xor(v, off, 64);
        const int   io = __shfl_xor(idx, off, 64);
        if (vo > v || (vo == v && io < idx)) { v = vo; idx = io; }
    }
    const float v1 = v; const int i1 = idx;

    float v2 = (lane == i1) ? -INFINITY : logit; int idx2 = lane;
#pragma unroll
    for (int off = 32; off >= 1; off >>= 1) {
        const float vo = __shfl_xor(v2, off, 64);
        const int   io = __shfl_xor(idx2, off, 64);
        if (vo > v2 || (vo == v2 && io < idx2)) { v2 = vo; idx2 = io; }
    }

    if (lane == 0) {
        const float e2 = expf(v2 - v1);       // <= 1
        const float g1 = 1.0f / (1.0f + e2);
        const float g2 = e2 * g1;
        outv[(size_t)row * 2 + 0] = g1;
        outv[(size_t)row * 2 + 1] = g2;
        outv[(size_t)2 * M_TOTAL + row * 2 + 0] = (float)i1;
        outv[(size_t)2 * M_TOTAL + row * 2 + 1] = (float)idx2;
    }
}

extern "C" void kernel_launch(void* const* d_in, const int* in_sizes, int n_in,
                              void* d_out, int out_size, void* d_ws, size_t ws_size,
                              hipStream_t stream)
{
    const float* x     = (const float*)d_in[0];
    const float* noise = (const float*)d_in[1];
    const float* w     = (const float*)d_in[2];
    const float* nw    = (const float*)d_in[3];
    // d_in[4] = top_k (==2), compile-time assumed

    const size_t plane_bytes = (size_t)M_TOTAL * EXP * sizeof(float);
    const size_t wpack_bytes = (size_t)786432 * 4;
    float* part = (float*)d_ws;

    if (ws_size >= 8 * plane_bytes + wpack_bytes) {
        uint32_t* wpack = (uint32_t*)((char*)d_ws + 8 * plane_bytes);
        wpack_prep<<<3072, 256, 0, stream>>>(w, nw, wpack);
        router_mfma8<8><<<dim3(128, 8), 256, 0, stream>>>(x, noise, wpack, part);
        topk_epilogue3<<<M_TOTAL / 4, 256, 0, stream>>>(part, 8, (float*)d_out);
    } else if (ws_size >= 4 * plane_bytes + wpack_bytes) {
        uint32_t* wpack = (uint32_t*)((char*)d_ws + 4 * plane_bytes);
        wpack_prep<<<3072, 256, 0, stream>>>(w, nw, wpack);
        router_mfma8<4><<<dim3(128, 4), 256, 0, stream>>>(x, noise, wpack, part);
        topk_epilogue3<<<M_TOTAL / 4, 256, 0, stream>>>(part, 4, (float*)d_out);
    } else {
        uint32_t* wpack = (uint32_t*)((char*)d_ws + 2 * plane_bytes);
        wpack_prep<<<3072, 256, 0, stream>>>(w, nw, wpack);
        router_mfma8<2><<<dim3(128, 2), 256, 0, stream>>>(x, noise, wpack, part);
        topk_epilogue3<<<M_TOTAL / 4, 256, 0, stream>>>(part, 2, (float*)d_out);
    }
}

// Round 12
// 180.874 us; speedup vs baseline: 1.3235x; 1.3235x over previous
//
#include <hip/hip_runtime.h>
#include <math.h>
#include <stdint.h>

#define M_TOTAL 16384
#define DDIM    4096
#define EXP     64

typedef __attribute__((ext_vector_type(8)))  short bf16x8;
typedef __attribute__((ext_vector_type(16))) float f32x16;

__device__ inline uint32_t fbits(float f){ union{float f;uint32_t u;}c; c.f=f; return c.u; }
__device__ inline float    bitsf(uint32_t u){ union{uint32_t u;float f;}c; c.u=u; return c.f; }
__device__ inline bf16x8   asfrag(uint4 t){ return __builtin_bit_cast(bf16x8, t); }

// ---------------------------------------------------------------------------
// W pre-pack: split w/nw into 3 bf16 planes (truncation split, exact to 2^-24)
// stored in MFMA-B-fragment-linear order:
//   word index = (((s*256 + kt)*2 + nt)*3 + pl)*256 + lane*4 + j
//   lane = (e&31) + 32*((k>>3)&1), word j holds k-elems 2j,2j+1
// ---------------------------------------------------------------------------
__global__ __launch_bounds__(256) void wpack_prep(
    const float* __restrict__ w, const float* __restrict__ nw,
    uint32_t* __restrict__ wpack)
{
    const int t = blockIdx.x * 256 + threadIdx.x;     // 786432 words total
    const int jw   = t & 3;
    const int lane = (t >> 2) & 63;
    const int rest = t >> 8;                          // ((s*256+kt)*2+nt)*3+pl
    const int pl   = rest % 3;
    const int r2   = rest / 3;
    const int nt   = r2 & 1;
    const int kt   = (r2 >> 1) & 255;
    const int s    = r2 >> 9;

    const int k0 = kt * 16 + (lane >> 5) * 8 + 2 * jw;
    const int e  = nt * 32 + (lane & 31);
    const float* __restrict__ src = s ? nw : w;
    float f0 = src[(size_t)k0 * EXP + e];
    float f1 = src[(size_t)(k0 + 1) * EXP + e];
    uint32_t u0 = fbits(f0), u1 = fbits(f1);
    for (int l = 0; l < pl; ++l) {                    // peel to level pl
        f0 -= bitsf(u0 & 0xFFFF0000u);
        f1 -= bitsf(u1 & 0xFFFF0000u);
        u0 = fbits(f0); u1 = fbits(f1);
    }
    wpack[t] = (u0 >> 16) | (u1 & 0xFFFF0000u);       // [lo=elem2j, hi=elem2j+1]
}

// ---------------------------------------------------------------------------
// MFMA GEMM: r6's proven barrier-dbuf structure, 4x longer DRAM runs.
// part[kp][row][e] = sum over k-plane of (x@w + noise@nw)
// BM=64, tile BK=64 k: A-tile 16 KB staged by 16 gl_lds instrs of 4 rows x
// 256 B CONTIGUOUS (4 sequential 128B lines per row visit). Double-buffered,
// ONE barrier per tile (4 ksteps). Wave = one 32x32 quadrant; W = 3 frags/
// kstep global->reg from L2-resident wpack (1-deep prefetch). XOR slot
// swizzle on stage-source + read (rule 21). LDS 32 KB -> 3 blocks/CU.
// ---------------------------------------------------------------------------
template<int KSPLIT>
__global__ __launch_bounds__(256, 3) void router_mfma9(
    const float* __restrict__ x, const float* __restrict__ noise,
    const uint32_t* __restrict__ wpack, float* __restrict__ part)
{
    constexpr int KRANGE = DDIM / KSPLIT;   // k per plane
    constexpr int VPS    = KRANGE / 16;     // ksteps per slice
    constexpr int NUt    = 2 * VPS;         // ksteps total
    constexpr int CPS    = KRANGE / 64;     // 64k tiles per slice
    constexpr int NT     = 2 * CPS;         // tiles total

    __shared__ float Al[2][64 * 64];        // [buf][row*64 + k] = 2 x 16 KB

    const int tid  = threadIdx.x;
    const int w_   = tid >> 6;
    const int lane = tid & 63;
    const int l31  = lane & 31;
    const int kh   = lane >> 5;             // k-half of the fragment
    const int mt   = w_ >> 1;               // wave quadrant: rows mt*32..+31
    const int nt   = w_ & 1;                //                experts nt*32..+31

    const int rowBase = blockIdx.x * 64;
    const int kp      = blockIdx.y;

    f32x16 acc, macc;
#pragma unroll
    for (int i = 0; i < 16; ++i) { acc[i] = 0.f; macc[i] = 0.f; }

    // ---- stage tile tt1 into Al[bufn]: wave w_ issues 4 instrs, each
    //      4 rows x 256 B contiguous; source slot XOR-permuted (involution)
    const int su = lane >> 4;               // row-in-quad
    const int sq = lane & 15;               // dest 16B slot within row
    auto stage = [&](int tt1, int bufn) {
        const int tc = (tt1 < NT) ? tt1 : (NT - 1);        // tail clamp
        const int sl = tc / CPS, ck = tc % CPS;
        const float* __restrict__ base = sl ? noise : x;
        const int k0 = kp * KRANGE + ck * 64;
#pragma unroll
        for (int i = 0; i < 4; ++i) {
            const int j    = w_ * 4 + i;                   // instr 0..15
            const int rloc = 4 * j + su;                   // row 0..63
            const int slog = sq ^ (rloc & 7);              // logical 16B slot
            const float* src = base + (size_t)(rowBase + rloc) * DDIM + k0 + slog * 4;
            __builtin_amdgcn_global_load_lds(
                (const __attribute__((address_space(1))) uint32_t*)src,
                (__attribute__((address_space(3))) uint32_t*)(&Al[bufn][j * 256]),
                16, 0, 0);
        }
    };
    auto wSrc = [&](int t) -> const uint32_t* {            // this wave's 3 frags
        const int tc = (t < NUt) ? t : (NUt - 1);          // tail clamp
        const int sl = tc / VPS, v = tc % VPS;
        return wpack + ((size_t)((sl * 256 + kp * VPS + v) * 2 + nt) * 3) * 256
                     + lane * 4;
    };

    // ---- read-side offsets (floats), static per phase after unroll
    const int r = mt * 32 + l31;            // this lane's A row
    int o0[4], o1[4];
#pragma unroll
    for (int p = 0; p < 4; ++p) {
        o0[p] = (r - mt * 32 + mt * 32) * 64 + ((4 * p + 2 * kh)     ^ (r & 7)) * 4;
        o1[p] = (r - mt * 32 + mt * 32) * 64 + ((4 * p + 2 * kh + 1) ^ (r & 7)) * 4;
        o0[p] += 0; o1[p] += 0;             // (r*64 kept explicit below)
    }
#pragma unroll
    for (int p = 0; p < 4; ++p) { o0[p] = r * 64 + (((4*p + 2*kh)   ^ (r & 7)) * 4);
                                  o1[p] = r * 64 + (((4*p + 2*kh+1) ^ (r & 7)) * 4); }

    uint4 wbuf[2][3];

    // ---- prologue: stage tile 0; W(0) -> wbuf[0]
    stage(0, 0);
    {
        const uint32_t* wp = wSrc(0);
#pragma unroll
        for (int f = 0; f < 3; ++f) wbuf[0][f] = *(const uint4*)(wp + f * 256);
    }
    __syncthreads();                        // tile 0 staged (drains vmcnt)

    int buf = 0;
    for (int tt = 0; tt < NT; ++tt) {
        stage(tt + 1, buf ^ 1);             // issue next tile's 4 KB early
#pragma unroll
        for (int p = 0; p < 4; ++p) {
            const int t = tt * 4 + p;

            // W(t+1) -> other parity: 3 dwordx4 from L2-resident wpack
            const uint32_t* wp = wSrc(t + 1);
#pragma unroll
            for (int f = 0; f < 3; ++f) wbuf[(p + 1) & 1][f] = *(const uint4*)(wp + f * 256);

            // A fragment from LDS (XOR slot; ~4-way b128, negligible)
            const float4 a0 = *(const float4*)&Al[buf][o0[p]];
            const float4 a1 = *(const float4*)&Al[buf][o1[p]];

            // split to 3 bf16 fragments (truncation split, exact to 2^-24)
            uint32_t fa1[4], fa2[4], fa3[4];
            const float in[8] = { a0.x, a0.y, a0.z, a0.w, a1.x, a1.y, a1.z, a1.w };
#pragma unroll
            for (int j = 0; j < 4; ++j) {
                const float a = in[2 * j], b = in[2 * j + 1];
                const uint32_t ha = fbits(a) & 0xFFFF0000u, hb = fbits(b) & 0xFFFF0000u;
                fa1[j] = (ha >> 16) | hb;
                const float ra = a - bitsf(ha), rb2 = b - bitsf(hb);
                const uint32_t ha2 = fbits(ra) & 0xFFFF0000u, hb2 = fbits(rb2) & 0xFFFF0000u;
                fa2[j] = (ha2 >> 16) | hb2;
                const float sa = ra - bitsf(ha2), sb = rb2 - bitsf(hb2);
                fa3[j] = (fbits(sa) >> 16) | (fbits(sb) & 0xFFFF0000u);
            }
            const bf16x8 a1f = asfrag(*(const uint4*)fa1);
            const bf16x8 a2f = asfrag(*(const uint4*)fa2);
            const bf16x8 a3f = asfrag(*(const uint4*)fa3);
            const bf16x8 b1  = asfrag(wbuf[p & 1][0]);
            const bf16x8 b2  = asfrag(wbuf[p & 1][1]);
            const bf16x8 b3  = asfrag(wbuf[p & 1][2]);

            f32x16 cc = acc;                // ascending-magnitude product order
            cc = __builtin_amdgcn_mfma_f32_32x32x16_bf16(a1f, b3, cc, 0, 0, 0);
            cc = __builtin_amdgcn_mfma_f32_32x32x16_bf16(a3f, b1, cc, 0, 0, 0);
            cc = __builtin_amdgcn_mfma_f32_32x32x16_bf16(a2f, b2, cc, 0, 0, 0);
            cc = __builtin_amdgcn_mfma_f32_32x32x16_bf16(a1f, b2, cc, 0, 0, 0);
            cc = __builtin_amdgcn_mfma_f32_32x32x16_bf16(a2f, b1, cc, 0, 0, 0);
            cc = __builtin_amdgcn_mfma_f32_32x32x16_bf16(a1f, b1, cc, 0, 0, 0);
            acc = cc;

            if (p == 3) {                   // drain 64-k window into masters
#pragma unroll
                for (int i = 0; i < 16; ++i) { macc[i] += acc[i]; acc[i] = 0.f; }
            }
        }
        __syncthreads();                    // next tile staged; buf reads done
        buf ^= 1;
    }

    // write plane; C/D layout (HW-verified): col=lane&31, row=(r&3)+8*(r>>2)+4*(lane>>5)
    float* __restrict__ out = part + (size_t)blockIdx.y * M_TOTAL * EXP;
#pragma unroll
    for (int r4 = 0; r4 < 16; ++r4) {
        const int orow = rowBase + mt * 32 + (r4 & 3) + 8 * (r4 >> 2) + 4 * kh;
        out[(size_t)orow * EXP + nt * 32 + l31] = macc[r4];
    }
}

// one wave per row: logits = f64 sum of planes; top-2 (jax tie-break: lower index
// wins); gates = 2-logit softmax == renormalized full softmax.
__global__ __launch_bounds__(256) void topk_epilogue3(
    const float* __restrict__ part, const int nplanes, float* __restrict__ outv)
{
    const int tid  = threadIdx.x;
    const int lane = tid & 63;
    const int row  = blockIdx.x * 4 + (tid >> 6);

    double sd = 0.0;
    for (int p = 0; p < nplanes; ++p)
        sd += (double)part[((size_t)p * M_TOTAL + row) * EXP + lane];
    const float logit = (float)sd;

    float v = logit; int idx = lane;
#pragma unroll
    for (int off = 32; off >= 1; off >>= 1) {
        const float vo = __shfl_xor(v, off, 64);
        const int   io = __shfl_xor(idx, off, 64);
        if (vo > v || (vo == v && io < idx)) { v = vo; idx = io; }
    }
    const float v1 = v; const int i1 = idx;

    float v2 = (lane == i1) ? -INFINITY : logit; int idx2 = lane;
#pragma unroll
    for (int off = 32; off >= 1; off >>= 1) {
        const float vo = __shfl_xor(v2, off, 64);
        const int   io = __shfl_xor(idx2, off, 64);
        if (vo > v2 || (vo == v2 && io < idx2)) { v2 = vo; idx2 = io; }
    }

    if (lane == 0) {
        const float e2 = expf(v2 - v1);       // <= 1
        const float g1 = 1.0f / (1.0f + e2);
        const float g2 = e2 * g1;
        outv[(size_t)row * 2 + 0] = g1;
        outv[(size_t)row * 2 + 1] = g2;
        outv[(size_t)2 * M_TOTAL + row * 2 + 0] = (float)i1;
        outv[(size_t)2 * M_TOTAL + row * 2 + 1] = (float)idx2;
    }
}

extern "C" void kernel_launch(void* const* d_in, const int* in_sizes, int n_in,
                              void* d_out, int out_size, void* d_ws, size_t ws_size,
                              hipStream_t stream)
{
    const float* x     = (const float*)d_in[0];
    const float* noise = (const float*)d_in[1];
    const float* w     = (const float*)d_in[2];
    const float* nw    = (const float*)d_in[3];
    // d_in[4] = top_k (==2), compile-time assumed

    const size_t plane_bytes = (size_t)M_TOTAL * EXP * sizeof(float);
    const size_t wpack_bytes = (size_t)786432 * 4;
    float* part = (float*)d_ws;

    if (ws_size >= 8 * plane_bytes + wpack_bytes) {
        uint32_t* wpack = (uint32_t*)((char*)d_ws + 8 * plane_bytes);
        wpack_prep<<<3072, 256, 0, stream>>>(w, nw, wpack);
        router_mfma9<8><<<dim3(256, 8), 256, 0, stream>>>(x, noise, wpack, part);
        topk_epilogue3<<<M_TOTAL / 4, 256, 0, stream>>>(part, 8, (float*)d_out);
    } else if (ws_size >= 4 * plane_bytes + wpack_bytes) {
        uint32_t* wpack = (uint32_t*)((char*)d_ws + 4 * plane_bytes);
        wpack_prep<<<3072, 256, 0, stream>>>(w, nw, wpack);
        router_mfma9<4><<<dim3(256, 4), 256, 0, stream>>>(x, noise, wpack, part);
        topk_epilogue3<<<M_TOTAL / 4, 256, 0, stream>>>(part, 4, (float*)d_out);
    } else {
        uint32_t* wpack = (uint32_t*)((char*)d_ws + 2 * plane_bytes);
        wpack_prep<<<3072, 256, 0, stream>>>(w, nw, wpack);
        router_mfma9<2><<<dim3(256, 2), 256, 0, stream>>>(x, noise, wpack, part);
        topk_epilogue3<<<M_TOTAL / 4, 256, 0, stream>>>(part, 2, (float*)d_out);
    }
}